// Round 6
// baseline (477.753 us; speedup 1.0000x reference)
//
#include <hip/hip_runtime.h>

typedef __attribute__((ext_vector_type(4))) float f32x4;
typedef __attribute__((ext_vector_type(8))) short s16x8;
typedef unsigned short u16;
typedef unsigned int   u32;

#define NBATCH 8
#define ICN 256
#define OCN 128
#define VOL 35937      // 33*33*33 dense upsampled volume per (n,oc)
#define PLANE 1089     // 33*33
#define WRE 884736     // 27*8*8*512 = 27*256*128
#define XTE 8388608    // 8*256*4096
#define S1POOL 33792   // max(per-plane A = 27200, transpose = 4*64*33*4 = 33792)

__device__ __forceinline__ u16 f2bf(float v){
  u32 u = __float_as_uint(v);
  u32 r = u + 0x7FFFu + ((u>>16)&1u);
  return (u16)(r>>16);
}
__device__ __forceinline__ float bf2f(u16 b){ return __uint_as_float(((u32)b)<<16); }

// ---- prep_w2: w[oc][ic][27] fp32 -> w2[tap27][icc8][og8][lane64][e8] bf16 hi/lo ----
__global__ __launch_bounds__(256) void prep_w2(const float* __restrict__ w,
                                               u16* __restrict__ wh, u16* __restrict__ wl){
  int idx = blockIdx.x*256 + threadIdx.x;   // WRE exactly
  int e = idx&7, ln=(idx>>3)&63, og=(idx>>9)&7, icc=(idx>>12)&7, tt=idx>>15;
  int oc = og*16 + (ln&15);
  int ic = icc*32 + ((ln>>4)&3)*8 + e;
  const int toffs[8] = {0,8,12,16,18,22,24,26};
  const int tcnt[8]  = {8,4,4,2,4,2,2,1};
  int c=0, t=0;
  #pragma unroll
  for (int cc=0; cc<8; ++cc)
    if (tt>=toffs[cc] && tt<toffs[cc]+tcnt[cc]){ c=cc; t=tt-toffs[cc]; }
  int ez=c>>2, ey=(c>>1)&1, ex=c&1;
  int ty=2-ey, tx=2-ex;
  int ax=t%tx, ay=(t/tx)%ty, az=t/(tx*ty);
  int qz = ez?1:(az?2:0), qy = ey?1:(ay?2:0), qx = ex?1:(ax?2:0);
  float v = w[((size_t)oc*ICN + ic)*27 + (qz*3+qy)*3+qx];
  u16 h = f2bf(v);
  wh[idx] = h;
  wl[idx] = f2bf(v - bf2f(h));
}

// ---- prep_x: x[n][ic][4096] fp32 -> x2[n][icc8][4096 pos][32 ic] bf16 hi/lo ----
__global__ __launch_bounds__(256) void prep_x(const float* __restrict__ x,
                                              u16* __restrict__ xh, u16* __restrict__ xl){
  u32 o = blockIdx.x*256 + threadIdx.x;   // XTE exactly
  int il = o & 31, p = (o>>5)&4095, icc = (o>>17)&7, n = o>>20;
  float v = x[(size_t)(n*256 + icc*32 + il)*4096 + p];
  u16 h = f2bf(v);
  xh[o] = h;
  xl[o] = f2bf(v - bf2f(h));
}

// ---- stage 1 body: per-class dense conv via split-bf16 MFMA; B-frags from L2 ----
// block 256 (4 waves): wave = (mhalf = wv&1)*64m x (ochalf = wv>>1)*64oc
template<int EZ,int EY,int EX>
__device__ __forceinline__ void s1body(char* pool,
                                       const u16* __restrict__ xh, const u16* __restrict__ xl,
                                       const u16* __restrict__ wh, const u16* __restrict__ wl,
                                       float* __restrict__ yd, int n0, int mt, int mz, int nl, int tid)
{
  constexpr int TZ=2-EZ, TY=2-EY, TX=2-EX;
  constexpr int DX=17-EX;
  constexpr int DY=17-EY;
  constexpr int NXY=DY*DX;
  constexpr int CLS = EZ*4+EY*2+EX;
  constexpr int W27 = (CLS==0)?0:(CLS==1)?8:(CLS==2)?12:(CLS==3)?16:
                      (CLS==4)?18:(CLS==5)?22:(CLS==6)?24:26;
  constexpr int AST   = 40;        // u16 per position (32 ic + 8 pad) -> 80 B
  constexpr int APOSP = 170;       // 10 rows x 17 x per plane
  constexpr int AHALFP= APOSP*AST; // u16 per half
  u16* As = (u16*)pool;

  const int wv=tid>>6, ln=tid&63;
  const int mhalf = wv&1, ochalf = wv>>1;
  const int my0=(mt*128)/DX;

  int posA[4];
  #pragma unroll
  for (int fi=0; fi<4; ++fi){
    int m = mt*128 + mhalf*64 + fi*16 + (ln&15);
    if (m > NXY-1) m = NXY-1;      // clamp (stores guarded)
    int my=m/DX, mx=m-my*DX;
    posA[fi] = ((my-my0)*17 + mx)*AST + (ln>>4)*8;
  }

  f32x4 acc[4][4];
  #pragma unroll
  for (int i=0;i<4;++i)
    #pragma unroll
    for (int j=0;j<4;++j) acc[i][j]=(f32x4){0.f,0.f,0.f,0.f};

  const size_t nbase = (size_t)(n0+nl)*(ICN*4096);

  #pragma unroll 1
  for (int icc=0; icc<8; ++icc){
    #pragma unroll
    for (int az=0; az<TZ; ++az){
      // stage one z-plane (hi+lo): 10 rows x 17 x, 32 ic each
      #pragma unroll 1
      for (int s=tid; s<APOSP*4; s+=256){
        int icg=s&3, pos=s>>2;
        int xi = pos%17, yi = pos/17;
        int zc = EZ ? mz : (mz-1+az);
        int yc = my0 + yi + (EY-1);
        int xc = xi + (EX-1);
        uint4 vh={0,0,0,0}, vlo={0,0,0,0};
        if ((u32)zc<16u && (u32)yc<16u && (u32)xc<16u){
          size_t g = nbase + (size_t)icc*131072 + (size_t)((zc*256+yc*16+xc)*32 + icg*8);
          vh  = *(const uint4*)(xh+g);
          vlo = *(const uint4*)(xl+g);
        }
        *(uint4*)&As[pos*AST + icg*8]          = vh;
        *(uint4*)&As[AHALFP + pos*AST + icg*8] = vlo;
      }
      __syncthreads();

      #pragma unroll
      for (int ay=0; ay<TY; ++ay)
      #pragma unroll
      for (int ax=0; ax<TX; ++ax){
        const int t = (az*TY+ay)*TX+ax;
        const int toff = (ay*17+ax)*AST;
        s16x8 ah[4], al[4];
        #pragma unroll
        for (int fi=0; fi<4; ++fi){
          ah[fi] = *(const s16x8*)&As[posA[fi]+toff];
          al[fi] = *(const s16x8*)&As[AHALFP+posA[fi]+toff];
        }
        const u16* bp = wh + (size_t)(((W27+t)*8+icc)*8)*512 + (ochalf*4)*512 + ln*8;
        const u16* bq = wl + (size_t)(((W27+t)*8+icc)*8)*512 + (ochalf*4)*512 + ln*8;
        s16x8 bh[4], bl[4];
        #pragma unroll
        for (int og=0; og<4; ++og) bh[og] = *(const s16x8*)(bp + og*512);
        #pragma unroll
        for (int og=0; og<4; ++og) bl[og] = *(const s16x8*)(bq + og*512);
        #pragma unroll
        for (int fi=0; fi<4; ++fi)
          #pragma unroll
          for (int og=0; og<4; ++og){
            acc[fi][og] = __builtin_amdgcn_mfma_f32_16x16x32_bf16(ah[fi], bh[og], acc[fi][og],0,0,0);
            acc[fi][og] = __builtin_amdgcn_mfma_f32_16x16x32_bf16(al[fi], bh[og], acc[fi][og],0,0,0);
            acc[fi][og] = __builtin_amdgcn_mfma_f32_16x16x32_bf16(ah[fi], bl[og], acc[fi][og],0,0,0);
          }
      }
      __syncthreads();
    }
  }

  // epilogue: per-wave transpose (2 half-passes of 32 m), dense stride-2 store
  float* tr = (float*)pool + wv*(64*33);
  const size_t ybn = (size_t)(nl*128)*VOL;
  #pragma unroll
  for (int pass=0; pass<2; ++pass){
    #pragma unroll
    for (int fi=0; fi<2; ++fi)
      #pragma unroll
      for (int og=0; og<4; ++og)
        #pragma unroll
        for (int j=0; j<4; ++j)
          tr[(og*16+(ln&15))*33 + fi*16 + (ln>>4)*4 + j] = acc[pass*2+fi][og][j];
    int m = mt*128 + mhalf*64 + pass*32 + (ln&31);
    bool valid = m < NXY;
    int mm = valid ? m : 0;
    int my=mm/DX, mx=mm-my*DX;
    int uz=2*mz+EZ, uy=2*my+EY, ux=2*mx+EX;
    size_t soff = (size_t)uz*PLANE + (size_t)uy*33 + ux;
    #pragma unroll 4
    for (int i=0; i<32; ++i){
      int r = 2*i + (ln>>5);
      float v = tr[r*33 + (ln&31)];
      int oc = ochalf*64 + r;
      if (valid) yd[ybn + (size_t)oc*VOL + soff] = v;
    }
  }
}

// ---- fused stage 1: mz-major, class-round-robin ordering ----
// bid in [0,363): mz = bid/22 (sub = bid%22), mz=16 has only EZ=0 classes (11 subs)
__global__ __launch_bounds__(256,4) void stage1f(const u16* __restrict__ xh, const u16* __restrict__ xl,
                                                 const u16* __restrict__ wh, const u16* __restrict__ wl,
                                                 float* __restrict__ yd, int n0){
  __shared__ __align__(16) char pool[S1POOL];
  const int bid = blockIdx.x, nl = blockIdx.z, tid = threadIdx.x;
  int mz, sub;
  if (bid < 352){ mz = bid/22; sub = bid - mz*22; }
  else          { mz = 16;     sub = bid - 352;   }
  if      (sub <  3) s1body<0,0,0>(pool,xh,xl,wh,wl,yd,n0,sub   ,mz,nl,tid);
  else if (sub <  6) s1body<0,0,1>(pool,xh,xl,wh,wl,yd,n0,sub- 3,mz,nl,tid);
  else if (sub <  9) s1body<0,1,0>(pool,xh,xl,wh,wl,yd,n0,sub- 6,mz,nl,tid);
  else if (sub < 11) s1body<0,1,1>(pool,xh,xl,wh,wl,yd,n0,sub- 9,mz,nl,tid);
  else if (sub < 14) s1body<1,0,0>(pool,xh,xl,wh,wl,yd,n0,sub-11,mz,nl,tid);
  else if (sub < 17) s1body<1,0,1>(pool,xh,xl,wh,wl,yd,n0,sub-14,mz,nl,tid);
  else if (sub < 20) s1body<1,1,0>(pool,xh,xl,wh,wl,yd,n0,sub-17,mz,nl,tid);
  else               s1body<1,1,1>(pool,xh,xl,wh,wl,yd,n0,sub-20,mz,nl,tid);
}

// ---- stage 2: dense separable FIR ([.25 .75 .75 .25] per axis) + bias ----
__global__ __launch_bounds__(256) void stage2d(const float* __restrict__ yd, const float* __restrict__ bias,
                                               float* __restrict__ out, int n0){
  __shared__ float raw[33][36];
  __shared__ float fx[35][36];
  const int tid=threadIdx.x;
  const int zg=blockIdx.x, oc=blockIdx.y, nl=blockIdx.z;
  const float* yb = yd + (size_t)(nl*128+oc)*VOL;
  const float b = bias[oc];
  float* ob = out + (size_t)((n0+nl)*128+oc)*32768;
  if (tid < 72){ fx[(tid>=36)?34:0][tid%36] = 0.f; }
  float a0[4]={0,0,0,0}, a1[4]={0,0,0,0}, a2[4]={0,0,0,0};
  #pragma unroll 1
  for (int s=0; s<19; ++s){
    int uz = zg*16 - 1 + s;
    for (int t2=tid; t2<1188; t2+=256){
      int uy = t2/36, uxm = t2 - uy*36, ux = uxm-1;
      float v = 0.f;
      if ((u32)uz<33u && (u32)ux<33u) v = yb[(size_t)uz*PLANE + uy*33 + ux];
      raw[uy][uxm] = v;
    }
    __syncthreads();
    for (int t2=tid; t2<1056; t2+=256){
      int uy = t2>>5, ox = t2&31;
      fx[uy+1][ox] = 0.25f*raw[uy][ox] + 0.75f*raw[uy][ox+1]
                   + 0.75f*raw[uy][ox+2] + 0.25f*raw[uy][ox+3];
    }
    __syncthreads();
    #pragma unroll
    for (int k=0;k<4;++k){
      int pos = tid + k*256;
      int oy = pos>>5, ox = pos&31;
      float fv = 0.25f*fx[oy][ox] + 0.75f*fx[oy+1][ox]
               + 0.75f*fx[oy+2][ox] + 0.25f*fx[oy+3][ox];
      if (s >= 3){
        int oz = zg*16 + s - 3;
        ob[(size_t)oz*1024 + pos] = a0[k] + 0.25f*fv + b;
      }
      a0[k] = a1[k] + 0.75f*fv;
      a1[k] = a2[k] + 0.75f*fv;
      a2[k] = 0.25f*fv;
    }
    __syncthreads();
  }
}

extern "C" void kernel_launch(void* const* d_in, const int* in_sizes, int n_in,
                              void* d_out, int out_size, void* d_ws, size_t ws_size,
                              hipStream_t stream) {
  const float* x    = (const float*)d_in[0];
  const float* w    = (const float*)d_in[1];
  const float* bias = (const float*)d_in[2];
  float* out = (float*)d_out;

  u16* wh = (u16*)d_ws;
  u16* wl = wh + WRE;
  u16* xh = wl + WRE;
  u16* xl = xh + XTE;
  float* yd = (float*)(xl + XTE);
  size_t base = (size_t)(2*WRE + 2*XTE)*2;

  int nChunk = 1;
  if      (ws_size >= base + (size_t)8*128*VOL*4) nChunk=8;
  else if (ws_size >= base + (size_t)4*128*VOL*4) nChunk=4;
  else if (ws_size >= base + (size_t)2*128*VOL*4) nChunk=2;

  prep_w2<<<dim3(WRE/256), 256, 0, stream>>>(w, wh, wl);
  prep_x<<<dim3(XTE/256), 256, 0, stream>>>(x, xh, xl);

  for (int n0=0; n0<NBATCH; n0+=nChunk){
    stage1f<<<dim3(363,1,nChunk),256,0,stream>>>(xh,xl,wh,wl,yd,n0);
    stage2d<<<dim3(2,128,nChunk),256,0,stream>>>(yd,bias,out,n0);
  }
}

// Round 7
// 432.754 us; speedup vs baseline: 1.1040x; 1.1040x over previous
//
#include <hip/hip_runtime.h>

typedef __attribute__((ext_vector_type(4))) float f32x4;
typedef __attribute__((ext_vector_type(8))) short s16x8;
typedef unsigned short u16;
typedef unsigned int   u32;

#define NBATCH 8
#define ICN 256
#define OCN 128
#define VOL 35937      // sum of per-class plane volumes per (n,oc)
#define WRE 884736     // 27*8*8*512 = 27*256*128
#define XTE 8388608    // 8*256*4096
#define S1POOL 33792   // max(per-plane A = 27200, transpose = 4*64*33*4 = 33792)

__host__ __device__ constexpr int cls_yoff(int c){
  return (c==0)?0:(c==1)?4913:(c==2)?9537:(c==3)?14161:
         (c==4)?18513:(c==5)?23137:(c==6)?27489:31841;
}

__device__ __forceinline__ u16 f2bf(float v){
  u32 u = __float_as_uint(v);
  u32 r = u + 0x7FFFu + ((u>>16)&1u);
  return (u16)(r>>16);
}
__device__ __forceinline__ float bf2f(u16 b){ return __uint_as_float(((u32)b)<<16); }

// ---- prep_w2: w[oc][ic][27] fp32 -> w2[tap27][icc8][og8][lane64][e8] bf16 hi/lo ----
__global__ __launch_bounds__(256) void prep_w2(const float* __restrict__ w,
                                               u16* __restrict__ wh, u16* __restrict__ wl){
  int idx = blockIdx.x*256 + threadIdx.x;   // WRE exactly
  int e = idx&7, ln=(idx>>3)&63, og=(idx>>9)&7, icc=(idx>>12)&7, tt=idx>>15;
  int oc = og*16 + (ln&15);
  int ic = icc*32 + ((ln>>4)&3)*8 + e;
  const int toffs[8] = {0,8,12,16,18,22,24,26};
  const int tcnt[8]  = {8,4,4,2,4,2,2,1};
  int c=0, t=0;
  #pragma unroll
  for (int cc=0; cc<8; ++cc)
    if (tt>=toffs[cc] && tt<toffs[cc]+tcnt[cc]){ c=cc; t=tt-toffs[cc]; }
  int ez=c>>2, ey=(c>>1)&1, ex=c&1;
  int ty=2-ey, tx=2-ex;
  int ax=t%tx, ay=(t/tx)%ty, az=t/(tx*ty);
  int qz = ez?1:(az?2:0), qy = ey?1:(ay?2:0), qx = ex?1:(ax?2:0);
  float v = w[((size_t)oc*ICN + ic)*27 + (qz*3+qy)*3+qx];
  u16 h = f2bf(v);
  wh[idx] = h;
  wl[idx] = f2bf(v - bf2f(h));
}

// ---- prep_x: x[n][ic][4096] fp32 -> x2[n][icc8][4096 pos][32 ic] bf16 hi/lo ----
__global__ __launch_bounds__(256) void prep_x(const float* __restrict__ x,
                                              u16* __restrict__ xh, u16* __restrict__ xl){
  u32 o = blockIdx.x*256 + threadIdx.x;   // XTE exactly
  int il = o & 31, p = (o>>5)&4095, icc = (o>>17)&7, n = o>>20;
  float v = x[(size_t)(n*256 + icc*32 + il)*4096 + p];
  u16 h = f2bf(v);
  xh[o] = h;
  xl[o] = f2bf(v - bf2f(h));
}

// ---- stage 1 body: per-class dense conv via split-bf16 MFMA; B-frags from L2 ----
// block 256 (4 waves): wave = (mhalf = wv&1)*64m x (ochalf = wv>>1)*64oc
template<int EZ,int EY,int EX>
__device__ __forceinline__ void s1body(char* pool,
                                       const u16* __restrict__ xh, const u16* __restrict__ xl,
                                       const u16* __restrict__ wh, const u16* __restrict__ wl,
                                       float* __restrict__ yd, int n0, int mt, int mz, int nl, int tid)
{
  constexpr int TZ=2-EZ, TY=2-EY, TX=2-EX;
  constexpr int DX=17-EX;
  constexpr int DY=17-EY;
  constexpr int NXY=DY*DX;
  constexpr int CLS = EZ*4+EY*2+EX;
  constexpr int YOFF = cls_yoff(CLS);
  constexpr int W27 = (CLS==0)?0:(CLS==1)?8:(CLS==2)?12:(CLS==3)?16:
                      (CLS==4)?18:(CLS==5)?22:(CLS==6)?24:26;
  constexpr int AST   = 40;        // u16 per position (32 ic + 8 pad) -> 80 B
  constexpr int APOSP = 170;       // 10 rows x 17 x per plane
  constexpr int AHALFP= APOSP*AST; // u16 per half
  u16* As = (u16*)pool;

  const int wv=tid>>6, ln=tid&63;
  const int mhalf = wv&1, ochalf = wv>>1;
  const int my0=(mt*128)/DX;

  int posA[4];
  #pragma unroll
  for (int fi=0; fi<4; ++fi){
    int m = mt*128 + mhalf*64 + fi*16 + (ln&15);
    if (m > NXY-1) m = NXY-1;      // clamp (stores guarded)
    int my=m/DX, mx=m-my*DX;
    posA[fi] = ((my-my0)*17 + mx)*AST + (ln>>4)*8;
  }

  f32x4 acc[4][4];
  #pragma unroll
  for (int i=0;i<4;++i)
    #pragma unroll
    for (int j=0;j<4;++j) acc[i][j]=(f32x4){0.f,0.f,0.f,0.f};

  const size_t nbase = (size_t)(n0+nl)*(ICN*4096);

  #pragma unroll 1
  for (int icc=0; icc<8; ++icc){
    #pragma unroll
    for (int az=0; az<TZ; ++az){
      // stage one z-plane (hi+lo): 10 rows x 17 x, 32 ic each
      #pragma unroll 1
      for (int s=tid; s<APOSP*4; s+=256){
        int icg=s&3, pos=s>>2;
        int xi = pos%17, yi = pos/17;
        int zc = EZ ? mz : (mz-1+az);
        int yc = my0 + yi + (EY-1);
        int xc = xi + (EX-1);
        uint4 vh={0,0,0,0}, vlo={0,0,0,0};
        if ((u32)zc<16u && (u32)yc<16u && (u32)xc<16u){
          size_t g = nbase + (size_t)icc*131072 + (size_t)((zc*256+yc*16+xc)*32 + icg*8);
          vh  = *(const uint4*)(xh+g);
          vlo = *(const uint4*)(xl+g);
        }
        *(uint4*)&As[pos*AST + icg*8]          = vh;
        *(uint4*)&As[AHALFP + pos*AST + icg*8] = vlo;
      }
      __syncthreads();

      #pragma unroll
      for (int ay=0; ay<TY; ++ay)
      #pragma unroll
      for (int ax=0; ax<TX; ++ax){
        const int t = (az*TY+ay)*TX+ax;
        const int toff = (ay*17+ax)*AST;
        s16x8 ah[4], al[4];
        #pragma unroll
        for (int fi=0; fi<4; ++fi){
          ah[fi] = *(const s16x8*)&As[posA[fi]+toff];
          al[fi] = *(const s16x8*)&As[AHALFP+posA[fi]+toff];
        }
        const u16* bp = wh + (size_t)(((W27+t)*8+icc)*8)*512 + (ochalf*4)*512 + ln*8;
        const u16* bq = wl + (size_t)(((W27+t)*8+icc)*8)*512 + (ochalf*4)*512 + ln*8;
        s16x8 bh[4], bl[4];
        #pragma unroll
        for (int og=0; og<4; ++og) bh[og] = *(const s16x8*)(bp + og*512);
        #pragma unroll
        for (int og=0; og<4; ++og) bl[og] = *(const s16x8*)(bq + og*512);
        #pragma unroll
        for (int fi=0; fi<4; ++fi)
          #pragma unroll
          for (int og=0; og<4; ++og){
            acc[fi][og] = __builtin_amdgcn_mfma_f32_16x16x32_bf16(ah[fi], bh[og], acc[fi][og],0,0,0);
            acc[fi][og] = __builtin_amdgcn_mfma_f32_16x16x32_bf16(al[fi], bh[og], acc[fi][og],0,0,0);
            acc[fi][og] = __builtin_amdgcn_mfma_f32_16x16x32_bf16(ah[fi], bl[og], acc[fi][og],0,0,0);
          }
      }
      __syncthreads();
    }
  }

  // epilogue: per-wave transpose (2 half-passes of 32 m), dense class-layout nt store
  float* tr = (float*)pool + wv*(64*33);
  #pragma unroll
  for (int pass=0; pass<2; ++pass){
    #pragma unroll
    for (int fi=0; fi<2; ++fi)
      #pragma unroll
      for (int og=0; og<4; ++og)
        #pragma unroll
        for (int j=0; j<4; ++j)
          tr[(og*16+(ln&15))*33 + fi*16 + (ln>>4)*4 + j] = acc[pass*2+fi][og][j];
    int m = mt*128 + mhalf*64 + pass*32 + (ln&31);
    bool valid = m < NXY;
    size_t lbase = (size_t)YOFF + (size_t)mz*NXY + (valid ? m : 0);
    #pragma unroll 4
    for (int i=0; i<32; ++i){
      int r = 2*i + (ln>>5);
      float v = tr[r*33 + (ln&31)];
      int oc = ochalf*64 + r;
      if (valid)
        __builtin_nontemporal_store(v, yd + (size_t)(nl*128 + oc)*VOL + lbase);
    }
  }
}

// ---- fused stage 1: mz-major, class-round-robin ordering ----
__global__ __launch_bounds__(256,4) void stage1f(const u16* __restrict__ xh, const u16* __restrict__ xl,
                                                 const u16* __restrict__ wh, const u16* __restrict__ wl,
                                                 float* __restrict__ yd, int n0){
  __shared__ __align__(16) char pool[S1POOL];
  const int bid = blockIdx.x, nl = blockIdx.z, tid = threadIdx.x;
  int mz, sub;
  if (bid < 352){ mz = bid/22; sub = bid - mz*22; }
  else          { mz = 16;     sub = bid - 352;   }
  if      (sub <  3) s1body<0,0,0>(pool,xh,xl,wh,wl,yd,n0,sub   ,mz,nl,tid);
  else if (sub <  6) s1body<0,0,1>(pool,xh,xl,wh,wl,yd,n0,sub- 3,mz,nl,tid);
  else if (sub <  9) s1body<0,1,0>(pool,xh,xl,wh,wl,yd,n0,sub- 6,mz,nl,tid);
  else if (sub < 11) s1body<0,1,1>(pool,xh,xl,wh,wl,yd,n0,sub- 9,mz,nl,tid);
  else if (sub < 14) s1body<1,0,0>(pool,xh,xl,wh,wl,yd,n0,sub-11,mz,nl,tid);
  else if (sub < 17) s1body<1,0,1>(pool,xh,xl,wh,wl,yd,n0,sub-14,mz,nl,tid);
  else if (sub < 20) s1body<1,1,0>(pool,xh,xl,wh,wl,yd,n0,sub-17,mz,nl,tid);
  else               s1body<1,1,1>(pool,xh,xl,wh,wl,yd,n0,sub-20,mz,nl,tid);
}

// ---- stage 2: gather parity subplanes (class-dense y) + separable FIR + bias ----
__global__ __launch_bounds__(256) void stage2d(const float* __restrict__ yd, const float* __restrict__ bias,
                                               float* __restrict__ out, int n0){
  __shared__ float raw[33][36];
  __shared__ float fx[35][36];
  const int tid=threadIdx.x;
  const int zg=blockIdx.x, oc=blockIdx.y, nl=blockIdx.z;
  const float* yb = yd + (size_t)(nl*128+oc)*VOL;
  const float b = bias[oc];
  float* ob = out + (size_t)((n0+nl)*128+oc)*32768;
  // one-time zero: raw padding cols (0,34,35) and whole array; fx pad rows
  for (int t2=tid; t2<1188; t2+=256) raw[t2/36][t2%36] = 0.f;
  if (tid < 72){ fx[(tid>=36)?34:0][tid%36] = 0.f; }
  __syncthreads();
  float a0[4]={0,0,0,0}, a1[4]={0,0,0,0}, a2[4]={0,0,0,0};
  #pragma unroll 1
  for (int s=0; s<19; ++s){
    int uz = zg*16 - 1 + s;
    if ((u32)uz < 33u){
      const int cz = uz & 1, zi = uz >> 1;
      #pragma unroll
      for (int cy=0; cy<2; ++cy)
        #pragma unroll
        for (int cx=0; cx<2; ++cx){
          constexpr int dummy = 0; (void)dummy;
          const int DYc = 17-cy, DXc = 17-cx;
          const int NXYc = DYc*DXc;
          const int yoff = (cz ? cls_yoff(4+cy*2+cx) : cls_yoff(cy*2+cx)) + zi*NXYc;
          const float* sp = yb + yoff;
          for (int s2=tid; s2<NXYc; s2+=256){
            int r = s2/DXc, c2 = s2 - r*DXc;
            raw[2*r+cy][2*c2+cx+1] = __builtin_nontemporal_load(sp + s2);
          }
        }
    } else {
      for (int t2=tid; t2<1188; t2+=256) raw[t2/36][t2%36] = 0.f;
    }
    __syncthreads();
    for (int t2=tid; t2<1056; t2+=256){
      int uy = t2>>5, ox = t2&31;
      fx[uy+1][ox] = 0.25f*raw[uy][ox] + 0.75f*raw[uy][ox+1]
                   + 0.75f*raw[uy][ox+2] + 0.25f*raw[uy][ox+3];
    }
    __syncthreads();
    #pragma unroll
    for (int k=0;k<4;++k){
      int pos = tid + k*256;
      int oy = pos>>5, ox = pos&31;
      float fv = 0.25f*fx[oy][ox] + 0.75f*fx[oy+1][ox]
               + 0.75f*fx[oy+2][ox] + 0.25f*fx[oy+3][ox];
      if (s >= 3){
        int oz = zg*16 + s - 3;
        __builtin_nontemporal_store(a0[k] + 0.25f*fv + b, ob + (size_t)oz*1024 + pos);
      }
      a0[k] = a1[k] + 0.75f*fv;
      a1[k] = a2[k] + 0.75f*fv;
      a2[k] = 0.25f*fv;
    }
    __syncthreads();
  }
}

extern "C" void kernel_launch(void* const* d_in, const int* in_sizes, int n_in,
                              void* d_out, int out_size, void* d_ws, size_t ws_size,
                              hipStream_t stream) {
  const float* x    = (const float*)d_in[0];
  const float* w    = (const float*)d_in[1];
  const float* bias = (const float*)d_in[2];
  float* out = (float*)d_out;

  u16* wh = (u16*)d_ws;
  u16* wl = wh + WRE;
  u16* xh = wl + WRE;
  u16* xl = xh + XTE;
  float* yd = (float*)(xl + XTE);
  size_t base = (size_t)(2*WRE + 2*XTE)*2;

  int nChunk = 1;
  if      (ws_size >= base + (size_t)8*128*VOL*4) nChunk=8;
  else if (ws_size >= base + (size_t)4*128*VOL*4) nChunk=4;
  else if (ws_size >= base + (size_t)2*128*VOL*4) nChunk=2;

  prep_w2<<<dim3(WRE/256), 256, 0, stream>>>(w, wh, wl);
  prep_x<<<dim3(XTE/256), 256, 0, stream>>>(x, xh, xl);

  for (int n0=0; n0<NBATCH; n0+=nChunk){
    stage1f<<<dim3(363,1,nChunk),256,0,stream>>>(xh,xl,wh,wl,yd,n0);
    stage2d<<<dim3(2,128,nChunk),256,0,stream>>>(yd,bias,out,n0);
  }
}

// Round 8
// 406.070 us; speedup vs baseline: 1.1765x; 1.0657x over previous
//
#include <hip/hip_runtime.h>

typedef __attribute__((ext_vector_type(4))) float f32x4;
typedef __attribute__((ext_vector_type(8))) short s16x8;
typedef unsigned short u16;
typedef unsigned int   u32;

#define NBATCH 8
#define ICN 256
#define OCN 128
#define VOLP 36432     // padded per-(n,oc) y volume (all classes, 16-float aligned)
#define WRE 884736     // 27*8*8*512 = 27*256*128
#define XTE 8388608    // 8*256*4096
#define S1POOL 33792   // max(per-plane A = 27200, transpose = 4*64*33*4 = 33792)

// padded class offsets / plane strides (16-float aligned)
__host__ __device__ constexpr int cls_yoff2(int c){
  return (c==0)?0:(c==1)?5168:(c==2)?9792:(c==3)?14416:
         (c==4)?18768:(c==5)?23632:(c==6)?27984:32336;
}
__host__ __device__ constexpr int cls_nxyp(int c){
  // (ey,ex): (0,0)->304, (0,1)->272, (1,0)->272, (1,1)->256
  return ((c&3)==0)?304:((c&3)==3)?256:272;
}

__device__ __forceinline__ u16 f2bf(float v){
  u32 u = __float_as_uint(v);
  u32 r = u + 0x7FFFu + ((u>>16)&1u);
  return (u16)(r>>16);
}
__device__ __forceinline__ float bf2f(u16 b){ return __uint_as_float(((u32)b)<<16); }

// ---- prep_w2: w[oc][ic][27] fp32 -> w2[tap27][icc8][og8][lane64][e8] bf16 hi/lo ----
__global__ __launch_bounds__(256) void prep_w2(const float* __restrict__ w,
                                               u16* __restrict__ wh, u16* __restrict__ wl){
  int idx = blockIdx.x*256 + threadIdx.x;   // WRE exactly
  int e = idx&7, ln=(idx>>3)&63, og=(idx>>9)&7, icc=(idx>>12)&7, tt=idx>>15;
  int oc = og*16 + (ln&15);
  int ic = icc*32 + ((ln>>4)&3)*8 + e;
  const int toffs[8] = {0,8,12,16,18,22,24,26};
  const int tcnt[8]  = {8,4,4,2,4,2,2,1};
  int c=0, t=0;
  #pragma unroll
  for (int cc=0; cc<8; ++cc)
    if (tt>=toffs[cc] && tt<toffs[cc]+tcnt[cc]){ c=cc; t=tt-toffs[cc]; }
  int ez=c>>2, ey=(c>>1)&1, ex=c&1;
  int ty=2-ey, tx=2-ex;
  int ax=t%tx, ay=(t/tx)%ty, az=t/(tx*ty);
  int qz = ez?1:(az?2:0), qy = ey?1:(ay?2:0), qx = ex?1:(ax?2:0);
  float v = w[((size_t)oc*ICN + ic)*27 + (qz*3+qy)*3+qx];
  u16 h = f2bf(v);
  wh[idx] = h;
  wl[idx] = f2bf(v - bf2f(h));
}

// ---- prep_x: x[n][ic][4096] fp32 -> x2[n][icc8][4096 pos][32 ic] bf16 hi/lo ----
__global__ __launch_bounds__(256) void prep_x(const float* __restrict__ x,
                                              u16* __restrict__ xh, u16* __restrict__ xl){
  u32 o = blockIdx.x*256 + threadIdx.x;   // XTE exactly
  int il = o & 31, p = (o>>5)&4095, icc = (o>>17)&7, n = o>>20;
  float v = x[(size_t)(n*256 + icc*32 + il)*4096 + p];
  u16 h = f2bf(v);
  xh[o] = h;
  xl[o] = f2bf(v - bf2f(h));
}

// ---- stage 1 body: per-class dense conv via split-bf16 MFMA; B-frags from L2 ----
// block 256 (4 waves): wave = (mhalf = wv&1)*64m x (ochalf = wv>>1)*64oc
template<int EZ,int EY,int EX>
__device__ __forceinline__ void s1body(char* pool,
                                       const u16* __restrict__ xh, const u16* __restrict__ xl,
                                       const u16* __restrict__ wh, const u16* __restrict__ wl,
                                       float* __restrict__ yd, int n0, int mt, int mz, int nl, int tid)
{
  constexpr int TZ=2-EZ, TY=2-EY, TX=2-EX;
  constexpr int DX=17-EX;
  constexpr int DY=17-EY;
  constexpr int NXY=DY*DX;
  constexpr int CLS = EZ*4+EY*2+EX;
  constexpr int YOFF = cls_yoff2(CLS);
  constexpr int NXYP = cls_nxyp(CLS);
  constexpr int W27 = (CLS==0)?0:(CLS==1)?8:(CLS==2)?12:(CLS==3)?16:
                      (CLS==4)?18:(CLS==5)?22:(CLS==6)?24:26;
  constexpr int AST   = 40;        // u16 per position (32 ic + 8 pad) -> 80 B
  constexpr int APOSP = 170;       // 10 rows x 17 x per plane
  constexpr int AHALFP= APOSP*AST; // u16 per half
  u16* As = (u16*)pool;

  const int wv=tid>>6, ln=tid&63;
  const int mhalf = wv&1, ochalf = wv>>1;
  const int my0=(mt*128)/DX;

  int posA[4];
  #pragma unroll
  for (int fi=0; fi<4; ++fi){
    int m = mt*128 + mhalf*64 + fi*16 + (ln&15);
    if (m > NXY-1) m = NXY-1;      // clamp (stores guarded)
    int my=m/DX, mx=m-my*DX;
    posA[fi] = ((my-my0)*17 + mx)*AST + (ln>>4)*8;
  }

  f32x4 acc[4][4];
  #pragma unroll
  for (int i=0;i<4;++i)
    #pragma unroll
    for (int j=0;j<4;++j) acc[i][j]=(f32x4){0.f,0.f,0.f,0.f};

  const size_t nbase = (size_t)(n0+nl)*(ICN*4096);

  #pragma unroll 1
  for (int icc=0; icc<8; ++icc){
    #pragma unroll
    for (int az=0; az<TZ; ++az){
      // stage one z-plane (hi+lo): 10 rows x 17 x, 32 ic each
      #pragma unroll 1
      for (int s=tid; s<APOSP*4; s+=256){
        int icg=s&3, pos=s>>2;
        int xi = pos%17, yi = pos/17;
        int zc = EZ ? mz : (mz-1+az);
        int yc = my0 + yi + (EY-1);
        int xc = xi + (EX-1);
        uint4 vh={0,0,0,0}, vlo={0,0,0,0};
        if ((u32)zc<16u && (u32)yc<16u && (u32)xc<16u){
          size_t g = nbase + (size_t)icc*131072 + (size_t)((zc*256+yc*16+xc)*32 + icg*8);
          vh  = *(const uint4*)(xh+g);
          vlo = *(const uint4*)(xl+g);
        }
        *(uint4*)&As[pos*AST + icg*8]          = vh;
        *(uint4*)&As[AHALFP + pos*AST + icg*8] = vlo;
      }
      __syncthreads();

      #pragma unroll
      for (int ay=0; ay<TY; ++ay)
      #pragma unroll
      for (int ax=0; ax<TX; ++ax){
        const int t = (az*TY+ay)*TX+ax;
        const int toff = (ay*17+ax)*AST;
        s16x8 ah[4], al[4];
        #pragma unroll
        for (int fi=0; fi<4; ++fi){
          ah[fi] = *(const s16x8*)&As[posA[fi]+toff];
          al[fi] = *(const s16x8*)&As[AHALFP+posA[fi]+toff];
        }
        const u16* bp = wh + (size_t)(((W27+t)*8+icc)*8)*512 + (ochalf*4)*512 + ln*8;
        const u16* bq = wl + (size_t)(((W27+t)*8+icc)*8)*512 + (ochalf*4)*512 + ln*8;
        s16x8 bh[4], bl[4];
        #pragma unroll
        for (int og=0; og<4; ++og) bh[og] = *(const s16x8*)(bp + og*512);
        #pragma unroll
        for (int og=0; og<4; ++og) bl[og] = *(const s16x8*)(bq + og*512);
        #pragma unroll
        for (int fi=0; fi<4; ++fi)
          #pragma unroll
          for (int og=0; og<4; ++og){
            acc[fi][og] = __builtin_amdgcn_mfma_f32_16x16x32_bf16(ah[fi], bh[og], acc[fi][og],0,0,0);
            acc[fi][og] = __builtin_amdgcn_mfma_f32_16x16x32_bf16(al[fi], bh[og], acc[fi][og],0,0,0);
            acc[fi][og] = __builtin_amdgcn_mfma_f32_16x16x32_bf16(ah[fi], bl[og], acc[fi][og],0,0,0);
          }
      }
      __syncthreads();
    }
  }

  // epilogue: per-wave transpose (2 half-passes of 32 m), aligned dense nt store
  float* tr = (float*)pool + wv*(64*33);
  #pragma unroll
  for (int pass=0; pass<2; ++pass){
    #pragma unroll
    for (int fi=0; fi<2; ++fi)
      #pragma unroll
      for (int og=0; og<4; ++og)
        #pragma unroll
        for (int j=0; j<4; ++j)
          tr[(og*16+(ln&15))*33 + fi*16 + (ln>>4)*4 + j] = acc[pass*2+fi][og][j];
    int m = mt*128 + mhalf*64 + pass*32 + (ln&31);
    bool valid = m < NXY;
    size_t lbase = (size_t)YOFF + (size_t)mz*NXYP + (valid ? m : 0);
    #pragma unroll 4
    for (int i=0; i<32; ++i){
      int r = 2*i + (ln>>5);
      float v = tr[r*33 + (ln&31)];
      int oc = ochalf*64 + r;
      if (valid)
        __builtin_nontemporal_store(v, yd + (size_t)(nl*128 + oc)*VOLP + lbase);
    }
  }
}

// ---- fused stage 1 ----
// gridDim.z==1 (XCD-swizzled): bid = idx*8 + nl -> XCD(bid%8) pinned to batch n
// else legacy: grid (363,1,nChunk)
__global__ __launch_bounds__(256,4) void stage1f(const u16* __restrict__ xh, const u16* __restrict__ xl,
                                                 const u16* __restrict__ wh, const u16* __restrict__ wl,
                                                 float* __restrict__ yd, int n0){
  __shared__ __align__(16) char pool[S1POOL];
  int bid = blockIdx.x, nl, tid = threadIdx.x;
  if (gridDim.z == 1){ nl = bid & 7; bid >>= 3; }
  else               { nl = blockIdx.z; }
  int mz, sub;
  if (bid < 352){ mz = bid/22; sub = bid - mz*22; }
  else          { mz = 16;     sub = bid - 352;   }
  if      (sub <  3) s1body<0,0,0>(pool,xh,xl,wh,wl,yd,n0,sub   ,mz,nl,tid);
  else if (sub <  6) s1body<0,0,1>(pool,xh,xl,wh,wl,yd,n0,sub- 3,mz,nl,tid);
  else if (sub <  9) s1body<0,1,0>(pool,xh,xl,wh,wl,yd,n0,sub- 6,mz,nl,tid);
  else if (sub < 11) s1body<0,1,1>(pool,xh,xl,wh,wl,yd,n0,sub- 9,mz,nl,tid);
  else if (sub < 14) s1body<1,0,0>(pool,xh,xl,wh,wl,yd,n0,sub-11,mz,nl,tid);
  else if (sub < 17) s1body<1,0,1>(pool,xh,xl,wh,wl,yd,n0,sub-14,mz,nl,tid);
  else if (sub < 20) s1body<1,1,0>(pool,xh,xl,wh,wl,yd,n0,sub-17,mz,nl,tid);
  else               s1body<1,1,1>(pool,xh,xl,wh,wl,yd,n0,sub-20,mz,nl,tid);
}

// ---- stage 2: gather parity subplanes (padded class-dense y) + separable FIR + bias ----
__global__ __launch_bounds__(256) void stage2d(const float* __restrict__ yd, const float* __restrict__ bias,
                                               float* __restrict__ out, int n0){
  __shared__ float raw[33][36];
  __shared__ float fx[35][36];
  const int tid=threadIdx.x;
  const int zg=blockIdx.x, oc=blockIdx.y, nl=blockIdx.z;
  const float* yb = yd + (size_t)(nl*128+oc)*VOLP;
  const float b = bias[oc];
  float* ob = out + (size_t)((n0+nl)*128+oc)*32768;
  for (int t2=tid; t2<1188; t2+=256) raw[t2/36][t2%36] = 0.f;
  if (tid < 72){ fx[(tid>=36)?34:0][tid%36] = 0.f; }
  __syncthreads();
  float a0[4]={0,0,0,0}, a1[4]={0,0,0,0}, a2[4]={0,0,0,0};
  #pragma unroll 1
  for (int s=0; s<19; ++s){
    int uz = zg*16 - 1 + s;
    if ((u32)uz < 33u){
      const int cz = uz & 1, zi = uz >> 1;
      #pragma unroll
      for (int cy=0; cy<2; ++cy)
        #pragma unroll
        for (int cx=0; cx<2; ++cx){
          const int DXc = 17-cx;
          const int NXYc = (17-cy)*DXc;
          const int NXYPc = cls_nxyp(cy*2+cx);
          const int yoff = (cz ? cls_yoff2(4+cy*2+cx) : cls_yoff2(cy*2+cx)) + zi*NXYPc;
          const float* sp = yb + yoff;
          for (int s2=tid; s2<NXYc; s2+=256){
            int r = s2/DXc, c2 = s2 - r*DXc;
            raw[2*r+cy][2*c2+cx+1] = __builtin_nontemporal_load(sp + s2);
          }
        }
    } else {
      for (int t2=tid; t2<1188; t2+=256) raw[t2/36][t2%36] = 0.f;
    }
    __syncthreads();
    for (int t2=tid; t2<1056; t2+=256){
      int uy = t2>>5, ox = t2&31;
      fx[uy+1][ox] = 0.25f*raw[uy][ox] + 0.75f*raw[uy][ox+1]
                   + 0.75f*raw[uy][ox+2] + 0.25f*raw[uy][ox+3];
    }
    __syncthreads();
    #pragma unroll
    for (int k=0;k<4;++k){
      int pos = tid + k*256;
      int oy = pos>>5, ox = pos&31;
      float fv = 0.25f*fx[oy][ox] + 0.75f*fx[oy+1][ox]
               + 0.75f*fx[oy+2][ox] + 0.25f*fx[oy+3][ox];
      if (s >= 3){
        int oz = zg*16 + s - 3;
        __builtin_nontemporal_store(a0[k] + 0.25f*fv + b, ob + (size_t)oz*1024 + pos);
      }
      a0[k] = a1[k] + 0.75f*fv;
      a1[k] = a2[k] + 0.75f*fv;
      a2[k] = 0.25f*fv;
    }
    __syncthreads();
  }
}

extern "C" void kernel_launch(void* const* d_in, const int* in_sizes, int n_in,
                              void* d_out, int out_size, void* d_ws, size_t ws_size,
                              hipStream_t stream) {
  const float* x    = (const float*)d_in[0];
  const float* w    = (const float*)d_in[1];
  const float* bias = (const float*)d_in[2];
  float* out = (float*)d_out;

  u16* wh = (u16*)d_ws;
  u16* wl = wh + WRE;
  u16* xh = wl + WRE;
  u16* xl = xh + XTE;
  float* yd = (float*)(xl + XTE);
  size_t base = (size_t)(2*WRE + 2*XTE)*2;

  int nChunk = 1;
  if      (ws_size >= base + (size_t)8*128*VOLP*4) nChunk=8;
  else if (ws_size >= base + (size_t)4*128*VOLP*4) nChunk=4;
  else if (ws_size >= base + (size_t)2*128*VOLP*4) nChunk=2;

  prep_w2<<<dim3(WRE/256), 256, 0, stream>>>(w, wh, wl);
  prep_x<<<dim3(XTE/256), 256, 0, stream>>>(x, xh, xl);

  if (nChunk == 8){
    stage1f<<<dim3(2904,1,1),256,0,stream>>>(xh,xl,wh,wl,yd,0);
    stage2d<<<dim3(2,128,8),256,0,stream>>>(yd,bias,out,0);
  } else {
    for (int n0=0; n0<NBATCH; n0+=nChunk){
      stage1f<<<dim3(363,1,nChunk),256,0,stream>>>(xh,xl,wh,wl,yd,n0);
      stage2d<<<dim3(2,128,nChunk),256,0,stream>>>(yd,bias,out,n0);
    }
  }
}